// Round 5
// baseline (242.777 us; speedup 1.0000x reference)
//
#include <hip/hip_runtime.h>

// GraphAttention fused forward for MI355X (gfx950), MFMA-based, barrier-free attn.
// B=4, N=2048, F=64, FP=32, H=4.  Output: [B,N,H*FP] f32 ++ uloss ++ eloss.

#define B_ 4
#define N_ 2048
#define F_ 64
#define FP_ 32
#define H_ 4
#define C_ 128
#define IT_ 16                 // i-rows per attn block
#define ITILES_ (N_ / IT_)     // 128
#define JCA_ 4                 // j-chunks (partial accumulation, occupancy)
#define JSPANA_ (N_ / JCA_)    // 512

typedef __attribute__((ext_vector_type(8))) short short8v;   // 8 bf16 = 4 VGPRs
typedef __attribute__((ext_vector_type(4))) float f32x4;     // MFMA C/D

__device__ __forceinline__ unsigned short f2bf(float f) {    // RNE fp32->bf16
    unsigned u = __float_as_uint(f);
    u += 0x7fffu + ((u >> 16) & 1u);
    return (unsigned short)(u >> 16);
}

// ---------------------------------------------------------------- kernel 1
// feats = x@W per head via MFMA; writes featsT bf16 [b][h][d][n] + s,t fp32.
// Block = (b, 64-row n-tile); 4 waves = 4 heads.
__global__ __launch_bounds__(256) void prep_kernel(
    const float* __restrict__ x, const float* __restrict__ W,
    const float* __restrict__ a_self, const float* __restrict__ a_neigh,
    unsigned short* __restrict__ featsT, float* __restrict__ sbuf,
    float* __restrict__ tbuf)
{
    int blk = blockIdx.x;              // b*32 + nt
    int b = blk >> 5, nt = blk & 31;
    int n0 = nt << 6;
    int t = threadIdx.x, h = t >> 6, lane = t & 63;
    int quad = lane >> 4, col = lane & 15;

    // B-frags: W[h][f][d] bf16; k=f packed as quad*8+e (same mapping as A)
    short8v bw[2][2];
    const float* Wh = W + (size_t)h * F_ * FP_;
#pragma unroll
    for (int kc = 0; kc < 2; ++kc)
#pragma unroll
        for (int dt = 0; dt < 2; ++dt)
#pragma unroll
            for (int e = 0; e < 8; ++e) {
                int f = kc * 32 + quad * 8 + e;
                bw[kc][dt][e] = (short)f2bf(Wh[f * FP_ + dt * 16 + col]);
            }
    float as0 = a_self[h * FP_ + col],  as1 = a_self[h * FP_ + 16 + col];
    float an0 = a_neigh[h * FP_ + col], an1 = a_neigh[h * FP_ + 16 + col];
    size_t hrow = ((size_t)b * H_ + h) * N_;
    size_t ftb  = ((size_t)b * H_ + h) * FP_;

    for (int ms = 0; ms < 4; ++ms) {
        int row = n0 + ms * 16 + col;          // A row m = lane&15
        const float* xr = x + ((size_t)b * N_ + row) * F_;
        f32x4 acc0 = {0.f, 0.f, 0.f, 0.f}, acc1 = {0.f, 0.f, 0.f, 0.f};
#pragma unroll
        for (int kc = 0; kc < 2; ++kc) {
            float4 x0 = *(const float4*)(xr + kc * 32 + quad * 8);
            float4 x1 = *(const float4*)(xr + kc * 32 + quad * 8 + 4);
            short8v av;
            av[0] = (short)f2bf(x0.x); av[1] = (short)f2bf(x0.y);
            av[2] = (short)f2bf(x0.z); av[3] = (short)f2bf(x0.w);
            av[4] = (short)f2bf(x1.x); av[5] = (short)f2bf(x1.y);
            av[6] = (short)f2bf(x1.z); av[7] = (short)f2bf(x1.w);
            acc0 = __builtin_amdgcn_mfma_f32_16x16x32_bf16(av, bw[kc][0], acc0, 0, 0, 0);
            acc1 = __builtin_amdgcn_mfma_f32_16x16x32_bf16(av, bw[kc][1], acc1, 0, 0, 0);
        }
        // C layout: row = quad*4+rr, col = lane&15 (verified m89/m91)
        {
            ushort4 v0, v1;
            v0.x = f2bf(acc0[0]); v0.y = f2bf(acc0[1]);
            v0.z = f2bf(acc0[2]); v0.w = f2bf(acc0[3]);
            v1.x = f2bf(acc1[0]); v1.y = f2bf(acc1[1]);
            v1.z = f2bf(acc1[2]); v1.w = f2bf(acc1[3]);
            size_t nidx = (size_t)n0 + ms * 16 + quad * 4;
            *(ushort4*)(featsT + (ftb + col) * N_ + nidx)      = v0;
            *(ushort4*)(featsT + (ftb + 16 + col) * N_ + nidx) = v1;
        }
#pragma unroll
        for (int rr = 0; rr < 4; ++rr) {
            float sv = acc0[rr] * as0 + acc1[rr] * as1;
            float tv = acc0[rr] * an0 + acc1[rr] * an1;
#pragma unroll
            for (int off = 8; off; off >>= 1) {
                sv += __shfl_down(sv, off);
                tv += __shfl_down(tv, off);
            }
            if (col == 0) {
                int n = n0 + ms * 16 + quad * 4 + rr;
                sbuf[hrow + n] = sv;
                tbuf[hrow + n] = tv;
            }
        }
    }
}

// ---------------------------------------------------------------- kernel 2
// Block = (b, 16-row i-tile, jc); 4 waves = 4 heads. NO LDS, NO barriers:
// adj/mask read from global directly in A-fragment layout (16 rows x 128 B
// per instr pair, coalesced; 4 head-waves hit the same lines in L1).
// P built in-register in MFMA A-layout, PV via mfma 16x16x32 bf16.
__global__ __launch_bounds__(256) void attn_kernel(
    const float* __restrict__ adj, const float* __restrict__ msk,
    const unsigned short* __restrict__ featsT,
    const float* __restrict__ sbuf, const float* __restrict__ tbuf,
    float* __restrict__ part, float* __restrict__ lpart)
{
    int blk = blockIdx.x;
    int jc = blk & (JCA_ - 1);
    int it = (blk >> 2) & (ITILES_ - 1);
    int b  = blk >> 9;
    int t = threadIdx.x, h = t >> 6, lane = t & 63;
    int quad = lane >> 4, r = lane & 15;
    int i0 = it * IT_;
    int jbase = jc * JSPANA_;

    size_t hrow = ((size_t)b * H_ + h) * N_;
    float si = sbuf[hrow + i0 + r];
    const float* trow = tbuf + hrow + jbase;
    const unsigned short* ft0 = featsT + (((size_t)b * H_ + h) * FP_ + r) * N_ + jbase;
    const unsigned short* ft1 = ft0 + (size_t)16 * N_;
    const float* adjb = adj + ((size_t)b * N_ + i0 + r) * N_ + jbase + quad * 8;
    const float* mskb = msk + ((size_t)b * N_ + i0 + r) * N_ + jbase + quad * 8;

    f32x4 acc0 = {0.f, 0.f, 0.f, 0.f}, acc1 = {0.f, 0.f, 0.f, 0.f};
    float l = 0.f, A = 0.f, nz = 0.f;

#pragma unroll 2
    for (int kc = 0; kc < JSPANA_ / 32; ++kc) {
        int jl = kc * 32 + quad * 8;          // j within span (A-frag k index)
        float4 a0 = *(const float4*)(adjb + kc * 32);
        float4 a1 = *(const float4*)(adjb + kc * 32 + 4);
        float4 m0 = *(const float4*)(mskb + kc * 32);
        float4 m1 = *(const float4*)(mskb + kc * 32 + 4);
        float4 t0 = *(const float4*)(trow + jl);
        float4 t1 = *(const float4*)(trow + jl + 4);
        short8v bv0 = *(const short8v*)(ft0 + jl);
        short8v bv1 = *(const short8v*)(ft1 + jl);
        float av[8] = {a0.x, a0.y, a0.z, a0.w, a1.x, a1.y, a1.z, a1.w};
        float mv[8] = {m0.x, m0.y, m0.z, m0.w, m1.x, m1.y, m1.z, m1.w};
        float tv[8] = {t0.x, t0.y, t0.z, t0.w, t1.x, t1.y, t1.z, t1.w};
        short8v ap;
#pragma unroll
        for (int q = 0; q < 8; ++q) {
            float dv = si + tv[q];
            dv = fmaxf(dv, 0.2f * dv);            // LeakyReLU(0.2)
            dv += mv[q];
            float e = __expf(dv);                 // bounded: no max-subtract
            float p = e * av[q];
            l += e; A += p;
            nz += (av[q] == 0.f ? 1.f : 0.f) - (p == 0.f ? 1.f : 0.f);
            ap[q] = (short)f2bf(p);
        }
        acc0 = __builtin_amdgcn_mfma_f32_16x16x32_bf16(ap, bv0, acc0, 0, 0, 0);
        acc1 = __builtin_amdgcn_mfma_f32_16x16x32_bf16(ap, bv1, acc1, 0, 0, 0);
    }
    // row totals live in lanes 0-15 after folding the 4 k-group lanes
    l  += __shfl_down(l, 32);  l  += __shfl_down(l, 16);
    A  += __shfl_down(A, 32);  A  += __shfl_down(A, 16);
    nz += __shfl_down(nz, 32); nz += __shfl_down(nz, 16);

    size_t pb = ((((size_t)(b * H_ + h) * ITILES_ + it) * JCA_ + jc) * 2) * 256;
    *(f32x4*)&part[pb + lane * 4]       = acc0;   // raw C-frag, coalesced
    *(f32x4*)&part[pb + 256 + lane * 4] = acc1;
    if (lane < 16) {
        size_t lb = (((size_t)(b * H_ + h) * ITILES_ + it) * JCA_ + jc) * 48;
        lpart[lb + lane]      = l;
        lpart[lb + 16 + lane] = A;
        lpart[lb + 32 + lane] = nz;
    }
}

// ---------------------------------------------------------------- kernel 3
// Block = (b, i-tile). Merge jc partials (raw C-frag layout), /l, bias, BN,
// ReLU, LDS transpose, coalesced out; per-(block,h) loss partials.
__global__ __launch_bounds__(256) void final_kernel(
    const float* __restrict__ part, const float* __restrict__ lpart,
    const float* __restrict__ bias, const float* __restrict__ gamma,
    const float* __restrict__ beta, const float* __restrict__ mmean,
    const float* __restrict__ mvar, float2* __restrict__ lossbuf,
    float* __restrict__ out)
{
    __shared__ float ldsl[H_ * 16];
    __shared__ float ldso[IT_ * 132];
    int blk = blockIdx.x;              // b*128 + it
    int b = blk >> 7, it = blk & 127;
    int t = threadIdx.x, h = t >> 6, lane = t & 63;
    int quad = lane >> 4, col = lane & 15;

    size_t pb = (((size_t)(b * H_ + h) * ITILES_ + it) * JCA_) * 512;
    f32x4 C0 = {0.f, 0.f, 0.f, 0.f}, C1 = {0.f, 0.f, 0.f, 0.f};
#pragma unroll
    for (int c = 0; c < JCA_; ++c) {
        C0 += *(const f32x4*)&part[pb + c * 512 + lane * 4];
        C1 += *(const f32x4*)&part[pb + c * 512 + 256 + lane * 4];
    }

    size_t lb = (((size_t)(b * H_ + h) * ITILES_ + it) * JCA_) * 48;
    if (lane < 16) {
        float lt = 0.f, At = 0.f, nzt = 0.f;
#pragma unroll
        for (int c = 0; c < JCA_; ++c) {
            lt  += lpart[lb + c * 48 + lane];
            At  += lpart[lb + c * 48 + 16 + lane];
            nzt += lpart[lb + c * 48 + 32 + lane];
        }
        ldsl[h * 16 + lane] = lt;
        float u = nzt, e = At / lt;
#pragma unroll
        for (int off = 8; off; off >>= 1) { u += __shfl_down(u, off); e += __shfl_down(e, off); }
        if (lane == 0) lossbuf[blk * H_ + h] = make_float2(u, e);
    }
    __syncthreads();
#pragma unroll
    for (int dt = 0; dt < 2; ++dt) {
        int c = h * FP_ + dt * 16 + col;
        float sc = rsqrtf(mvar[c] + 1e-3f) * gamma[c];
        float sh = beta[c] - mmean[c] * sc;
        float bi = bias[c];
        f32x4 Cv = dt ? C1 : C0;
#pragma unroll
        for (int rr = 0; rr < 4; ++rr) {
            int row = quad * 4 + rr;
            float node = Cv[rr] / ldsl[h * 16 + row] + bi;
            float o = node * sc + sh;
            ldso[row * 132 + c] = o > 0.f ? o : 0.f;
        }
    }
    __syncthreads();
#pragma unroll
    for (int ps = 0; ps < 2; ++ps) {
        int row = ps * 8 + (t >> 5);
        int c4 = (t & 31) * 4;
        *(float4*)(out + ((size_t)b * N_ + it * IT_ + row) * C_ + c4) =
            *(const float4*)&ldso[row * 132 + c4];
    }
}

// ---------------------------------------------------------------- kernel 4
__global__ __launch_bounds__(256) void loss_kernel(
    const float2* __restrict__ lossbuf, float* __restrict__ out)
{
    float u = 0.f, e = 0.f;
    for (int idx = threadIdx.x; idx < B_ * ITILES_ * H_; idx += 256) {
        float2 v = lossbuf[idx];
        u += v.x; e += v.y;
    }
    __shared__ float su[256], se[256];
    su[threadIdx.x] = u; se[threadIdx.x] = e;
    __syncthreads();
    for (int o = 128; o; o >>= 1) {
        if (threadIdx.x < o) {
            su[threadIdx.x] += su[threadIdx.x + o];
            se[threadIdx.x] += se[threadIdx.x + o];
        }
        __syncthreads();
    }
    if (threadIdx.x == 0) {
        out[(size_t)B_ * N_ * C_]     = su[0] * (1.f / N_);  // uloss
        out[(size_t)B_ * N_ * C_ + 1] = se[0] * (1.f / N_);  // eloss
    }
}

// ---------------------------------------------------------------- launch
extern "C" void kernel_launch(void* const* d_in, const int* in_sizes, int n_in,
                              void* d_out, int out_size, void* d_ws, size_t ws_size,
                              hipStream_t stream)
{
    const float* x         = (const float*)d_in[0];
    const float* adj       = (const float*)d_in[1];
    const float* attn_mask = (const float*)d_in[2];
    const float* W         = (const float*)d_in[3];
    const float* a_self    = (const float*)d_in[4];
    const float* a_neigh   = (const float*)d_in[5];
    const float* bias      = (const float*)d_in[6];
    const float* gamma     = (const float*)d_in[7];
    const float* beta      = (const float*)d_in[8];
    const float* mmean     = (const float*)d_in[9];
    const float* mvar      = (const float*)d_in[10];
    float* out = (float*)d_out;

    float* ws = (float*)d_ws;
    unsigned short* featsT = (unsigned short*)ws;                     // 1,048,576 u16
    float* sbuf  = ws + 524288;                                       //    32,768 f
    float* tbuf  = sbuf + (size_t)B_ * H_ * N_;                       //    32,768 f
    float* part  = tbuf + (size_t)B_ * H_ * N_;                       // 4,194,304 f
    float* lpart = part + (size_t)B_ * H_ * ITILES_ * JCA_ * 2 * 256; //   393,216 f
    float* lossb = lpart + (size_t)B_ * H_ * ITILES_ * JCA_ * 48;     //     4,096 f

    hipLaunchKernelGGL(prep_kernel, dim3(B_ * 32), dim3(256), 0, stream,
                       x, W, a_self, a_neigh, featsT, sbuf, tbuf);
    hipLaunchKernelGGL(attn_kernel, dim3(B_ * ITILES_ * JCA_), dim3(256), 0, stream,
                       adj, attn_mask, featsT, sbuf, tbuf, part, lpart);
    hipLaunchKernelGGL(final_kernel, dim3(B_ * ITILES_), dim3(256), 0, stream,
                       part, lpart, bias, gamma, beta, mmean, mvar,
                       (float2*)lossb, out);
    hipLaunchKernelGGL(loss_kernel, dim3(1), dim3(256), 0, stream,
                       (const float2*)lossb, out);
}